// Round 7
// baseline (332.360 us; speedup 1.0000x reference)
//
#include <hip/hip_runtime.h>
#include <hip/hip_bf16.h>
#include <math.h>

#define N_NODES 3072
#define NPAD    3104    // V^T column stride: N + 32 zeroed pad cols (aligned PV loads)
#define DIM     256
#define NH      8
#define HD      32
#define E_EDGES 98304
#define B_GRAPHS 16
#define RCAP    96      // per-row bucket capacity (mean 32, 11-sigma margin; fixed seed)
#define MAXC    332     // fp32 score stride: 332*4=1328B rows (16B-aligned float4 P reads)
#define TR      16      // rows per attention tile
#define NTILE   24      // row tiles per graph (worst case)
#define SCALE   0.17677669529663689f   // 1/sqrt(32)

typedef __attribute__((ext_vector_type(8))) short bf16x8;
typedef __attribute__((ext_vector_type(4))) float f32x4;
typedef __attribute__((ext_vector_type(4))) unsigned short ushort4v;

__device__ inline unsigned short f2b(float f) {
    __hip_bfloat16 h = __float2bfloat16(f);
    return *reinterpret_cast<unsigned short*>(&h);
}
__device__ inline float b2f(unsigned short u) {
    __hip_bfloat16 h = *reinterpret_cast<__hip_bfloat16*>(&u);
    return __bfloat162float(h);
}

// ======================= phase bodies (proven R1/R3) ==========================

__device__ inline void xsplit_body(int u, int t, const float* __restrict__ x,
                                   unsigned short* __restrict__ xh,
                                   unsigned short* __restrict__ xl) {
    const int gid = u * 256 + t;
    float4 v = ((const float4*)x)[gid];
    ushort4v h, l;
    float c[4] = {v.x, v.y, v.z, v.w};
    #pragma unroll
    for (int i = 0; i < 4; ++i) {
        unsigned short hi = f2b(c[i]);
        h[i] = hi;
        l[i] = f2b(c[i] - b2f(hi));
    }
    ((ushort4v*)xh)[gid] = h;
    ((ushort4v*)xl)[gid] = l;
}

__device__ inline void wtrans_body(int wb, int t,
                                   const float* __restrict__ Wq, const float* __restrict__ Wk,
                                   const float* __restrict__ Wv, const float* __restrict__ Wo,
                                   unsigned short* __restrict__ Wth,
                                   unsigned short* __restrict__ Wtl,
                                   float (*tile)[33]) {
    const int mat = wb >> 6, tidx = wb & 63;
    const int tk = (tidx >> 3) * 32, tn = (tidx & 7) * 32;
    const float* W = (mat == 0) ? Wq : (mat == 1) ? Wk : (mat == 2) ? Wv : Wo;
    const int kk = t >> 5, nn = t & 31;
    #pragma unroll
    for (int p = 0; p < 4; ++p)
        tile[nn][kk + p * 8] = W[(size_t)(tk + kk + p * 8) * DIM + tn + nn];
    __syncthreads();
    const int n = t >> 3, kq = (t & 7) * 4;
    ushort4v h, l;
    #pragma unroll
    for (int i = 0; i < 4; ++i) {
        float v = tile[n][kq + i];
        unsigned short hi = f2b(v);
        h[i] = hi;
        l[i] = f2b(v - b2f(hi));
    }
    size_t o = (size_t)mat * DIM * DIM + (size_t)(tn + n) * DIM + tk + kq;
    *(ushort4v*)(Wth + o) = h;
    *(ushort4v*)(Wtl + o) = l;
}

__device__ inline void vtpad_body(int i, const int* __restrict__ batch,
                                  unsigned short* __restrict__ VT,
                                  int* __restrict__ gstart) {
    VT[(size_t)(i >> 5) * NPAD + N_NODES + (i & 31)] = 0;   // i in [0, 8192)
    if (i < N_NODES) {
        int bb = batch[i];
        int bp = (i == 0) ? -1 : batch[i - 1];
        for (int g = bp + 1; g <= bb; ++g) gstart[g] = i;
        if (i == N_NODES - 1)
            for (int g = bb + 1; g <= B_GRAPHS; ++g) gstart[g] = N_NODES;
    }
}

// edge bucket insert only — ebias is now computed on the fly in attn_go.
__device__ inline void edge_body(int e,
                                 const int* __restrict__ erow, const int* __restrict__ ecolin,
                                 int* __restrict__ tcur, unsigned int* __restrict__ tbuck) {
    const int row = erow[e];
    const int col = ecolin[e];
    int pos = atomicAdd(&tcur[row], 1);
    if (pos < RCAP)
        tbuck[(size_t)row * RCAP + pos] = ((unsigned int)e << 12) | (unsigned int)col;
}

// wave tile 16x32; u in [0,1152): bx=u%96 (32-row block), by=u/96, mat=by>>2.
__device__ inline void qkv_body(int u, int t,
                                const unsigned short* __restrict__ xh, const unsigned short* __restrict__ xl,
                                const unsigned short* __restrict__ Wth, const unsigned short* __restrict__ Wtl,
                                const float* __restrict__ bq, const float* __restrict__ bk,
                                const float* __restrict__ bv,
                                unsigned short* __restrict__ Qb, unsigned short* __restrict__ Kb,
                                unsigned short* __restrict__ VT) {
    const int w = t >> 6, lane = t & 63;
    const int l16 = lane & 15, lq = lane >> 4;
    const int bx = u % 96, by = u / 96;
    const int mat = by >> 2;
    const int rb = bx * 32 + (w & 1) * 16;
    const int nb = (by & 3) * 64 + (w >> 1) * 32;
    const unsigned short* Wh = Wth + (size_t)mat * DIM * DIM;
    const unsigned short* Wl = Wtl + (size_t)mat * DIM * DIM;

    f32x4 acc[2] = {{0,0,0,0},{0,0,0,0}};

    if (mat < 2) {                       // ---- Q/K: A = x rows, B = W^T rows
        const size_t arow = (size_t)(rb + l16) * DIM + (lq << 3);
        #pragma unroll
        for (int kc = 0; kc < 8; ++kc) {
            const int k = kc * 32;
            bf16x8 ah = *(const bf16x8*)(xh + arow + k);
            bf16x8 al = *(const bf16x8*)(xl + arow + k);
            #pragma unroll
            for (int ct = 0; ct < 2; ++ct) {
                const size_t bo_ = (size_t)(nb + ct * 16 + l16) * DIM + k + (lq << 3);
                bf16x8 bh = *(const bf16x8*)(Wh + bo_);
                bf16x8 bl = *(const bf16x8*)(Wl + bo_);
                acc[ct] = __builtin_amdgcn_mfma_f32_16x16x32_bf16(ah, bh, acc[ct], 0, 0, 0);
                acc[ct] = __builtin_amdgcn_mfma_f32_16x16x32_bf16(ah, bl, acc[ct], 0, 0, 0);
                acc[ct] = __builtin_amdgcn_mfma_f32_16x16x32_bf16(al, bh, acc[ct], 0, 0, 0);
            }
        }
        const float* bias = (mat == 0) ? bq : bk;
        unsigned short* outp = (mat == 0) ? Qb : Kb;
        #pragma unroll
        for (int ct = 0; ct < 2; ++ct) {
            const int n = nb + ct * 16 + l16;
            const float bvl = bias[n];
            #pragma unroll
            for (int r = 0; r < 4; ++r)
                outp[(size_t)(rb + lq * 4 + r) * DIM + n] = f2b(acc[ct][r] + bvl);
        }
    } else {                             // ---- V^T: A = Wv^T rows, B = x rows
        const size_t brow = (size_t)(rb + l16) * DIM + (lq << 3);
        #pragma unroll
        for (int kc = 0; kc < 8; ++kc) {
            const int k = kc * 32;
            bf16x8 bxh = *(const bf16x8*)(xh + brow + k);
            bf16x8 bxl = *(const bf16x8*)(xl + brow + k);
            #pragma unroll
            for (int ct = 0; ct < 2; ++ct) {
                const size_t ao_ = (size_t)(nb + ct * 16 + l16) * DIM + k + (lq << 3);
                bf16x8 awh = *(const bf16x8*)(Wh + ao_);
                bf16x8 awl = *(const bf16x8*)(Wl + ao_);
                acc[ct] = __builtin_amdgcn_mfma_f32_16x16x32_bf16(awh, bxh, acc[ct], 0, 0, 0);
                acc[ct] = __builtin_amdgcn_mfma_f32_16x16x32_bf16(awh, bxl, acc[ct], 0, 0, 0);
                acc[ct] = __builtin_amdgcn_mfma_f32_16x16x32_bf16(awl, bxh, acc[ct], 0, 0, 0);
            }
        }
        #pragma unroll
        for (int ct = 0; ct < 2; ++ct) {
            #pragma unroll
            for (int r = 0; r < 4; ++r) {
                const int ncol = nb + ct * 16 + lq * 4 + r;   // output channel (h*HD+kout)
                VT[(size_t)ncol * NPAD + rb + l16] = f2b(acc[ct][r] + bv[ncol]);
            }
        }
    }
}

// ======================= node 1: x-split | W-trans | tcur/pcnt zero ===========
// grid 1038: [0,768) x-split, [768,1024) W-transpose, [1024,1038) zero tcur+pcnt.
__global__ __launch_bounds__(256) void prep_a(
    const float* __restrict__ x,
    const float* __restrict__ Wq, const float* __restrict__ Wk,
    const float* __restrict__ Wv, const float* __restrict__ Wo,
    unsigned short* __restrict__ xh, unsigned short* __restrict__ xl,
    unsigned short* __restrict__ Wth, unsigned short* __restrict__ Wtl,
    int* __restrict__ tcur, unsigned int* __restrict__ pcnt)
{
    __shared__ float tile[32][33];
    const int b = blockIdx.x, t = threadIdx.x;
    if (b < 768)        xsplit_body(b, t, x, xh, xl);
    else if (b < 1024)  wtrans_body(b - 768, t, Wq, Wk, Wv, Wo, Wth, Wtl, tile);
    else {
        const int i = (b - 1024) * 256 + t;          // [0, 3584)
        if (i < N_NODES)                tcur[i] = 0;
        else if (i < N_NODES + B_GRAPHS * NTILE) pcnt[i - N_NODES] = 0u;
    }
}

// ======================= node 2: edges | qkv mfma | VT-pad/gstart =============
__global__ __launch_bounds__(256) void stage2(
    const unsigned short* __restrict__ xh, const unsigned short* __restrict__ xl,
    const unsigned short* __restrict__ Wth, const unsigned short* __restrict__ Wtl,
    const float* __restrict__ bq, const float* __restrict__ bk,
    const float* __restrict__ bv,
    const int* __restrict__ erow, const int* __restrict__ ecolin,
    const int* __restrict__ batch,
    unsigned short* __restrict__ Qb, unsigned short* __restrict__ Kb,
    unsigned short* __restrict__ VT,
    int* __restrict__ gstart, int* __restrict__ tcur, unsigned int* __restrict__ tbuck)
{
    const int b = blockIdx.x, t = threadIdx.x;
    if (b < 384)        edge_body(b * 256 + t, erow, ecolin, tcur, tbuck);
    else if (b < 1536)  qkv_body(b - 384, t, xh, xl, Wth, Wtl, bq, bk, bv, Qb, Kb, VT);
    else                vtpad_body((b - 1536) * 256 + t, batch, VT, gstart);
}

// ======================= node 3: attention + last-arriver out-projection ======
// grid (16,24,8) = 3072 blocks (one head each, full parallelism restored).
// Each head-block: QK^T -> on-the-fly edge bias -> softmax -> PV -> writes its
// fp32 slice to global pre[N][256], fences, bumps pcnt[(g,tile)]. The 8th
// arriver (no spinning — others exit) acquires and runs the out-GEMM for the
// tile, reading pre and hi/lo-splitting in regs (R6-validated, bitwise-identical).
__global__ __launch_bounds__(256) void attn_go(
    const unsigned short* __restrict__ Qb, const unsigned short* __restrict__ Kb,
    const unsigned short* __restrict__ VT,
    const int* __restrict__ gstart,
    const int* __restrict__ tcur, const unsigned int* __restrict__ tbuck,
    const float* __restrict__ ea, const float* __restrict__ We,
    const float* __restrict__ be,
    const unsigned short* __restrict__ Wth, const unsigned short* __restrict__ Wtl,
    const float* __restrict__ bo,
    float* __restrict__ pre, unsigned int* __restrict__ pcnt,
    float* __restrict__ out)
{
    __shared__ __align__(16) float s[TR][MAXC];   // scores/P/reduce, 21.3 KB
    __shared__ float rowinv[TR];
    __shared__ int isLast;

    const int g = blockIdx.x, tile_ = blockIdx.y, h = blockIdx.z;
    const int gs = gstart[g], ge = gstart[g + 1];
    const int row0 = gs + tile_ * TR;
    if (row0 >= ge) return;                       // block-uniform; pcnt stays 0 (no out rows)
    const int nrows = min(TR, ge - row0);
    const int ncols = ge - gs;
    const int ags   = gs & ~15;
    const int coff  = gs - ags;
    const int tcols = coff + ncols;
    const int cpad  = (tcols + 31) & ~31;
    const int t = threadIdx.x;
    const int wave = t >> 6, lane = t & 63;
    const int l16 = lane & 15, lq = lane >> 4;

    // per-head We column + bias (broadcast scalar loads)
    const float we0 = We[0 * NH + h], we1 = We[1 * NH + h];
    const float we2 = We[2 * NH + h], we3 = We[3 * NH + h];
    const float beh = be[h];

    // ---- QK^T via MFMA
    {
        int arow = min(row0 + l16, N_NODES - 1);
        const bf16x8 aq = *(const bf16x8*)(Qb + (size_t)arow * DIM + h * HD + (lq << 3));
        const int nchunk16 = (tcols + 15) >> 4;
        for (int j = wave; j < nchunk16; j += 4) {
            const int c0 = j << 4;
            int krow = min(ags + c0 + l16, N_NODES - 1);
            bf16x8 bk = *(const bf16x8*)(Kb + (size_t)krow * DIM + h * HD + (lq << 3));
            f32x4 d = {0.f, 0.f, 0.f, 0.f};
            d = __builtin_amdgcn_mfma_f32_16x16x32_bf16(aq, bk, d, 0, 0, 0);
            const int col = c0 + l16, rbase = lq * 4;
            #pragma unroll
            for (int r = 0; r < 4; ++r) s[rbase + r][col] = d[r] * SCALE;
        }
    }
    __syncthreads();

    // ---- edge-bias scatter, bias computed on the fly (same fmaf chain as before)
    {
        const int r = t >> 4, sub = t & 15;
        if (r < nrows) {
            const int cnt = min(tcur[row0 + r], RCAP);
            const unsigned int* bk = tbuck + (size_t)(row0 + r) * RCAP;
            for (int idx = sub; idx < cnt; idx += 16) {
                unsigned int p = bk[idx];
                int c = (int)(p & 0xFFFu) - gs;
                if (c >= 0 && c < ncols) {
                    float4 a = ((const float4*)ea)[p >> 12];
                    float bb = fmaf(a.x, we0, fmaf(a.y, we1,
                               fmaf(a.z, we2, fmaf(a.w, we3, beh))));
                    atomicAdd(&s[r][coff + c], bb);
                }
            }
        }
    }
    __syncthreads();

    // ---- softmax, exp written back in place (fp32 P)
    {
        const int r = t >> 4, sub = t & 15;
        if (r < nrows) {
            float m = -INFINITY;
            for (int c = coff + sub; c < tcols; c += 16) m = fmaxf(m, s[r][c]);
            m = fmaxf(m, __shfl_xor(m, 1, 16));
            m = fmaxf(m, __shfl_xor(m, 2, 16));
            m = fmaxf(m, __shfl_xor(m, 4, 16));
            m = fmaxf(m, __shfl_xor(m, 8, 16));
            float sum = 0.f;
            for (int c = sub; c < cpad; c += 16) {
                float e = 0.f;
                if (c >= coff && c < tcols) e = __expf(s[r][c] - m);
                sum += e;
                s[r][c] = e;
            }
            sum += __shfl_xor(sum, 1, 16);
            sum += __shfl_xor(sum, 2, 16);
            sum += __shfl_xor(sum, 4, 16);
            sum += __shfl_xor(sum, 8, 16);
            if (sub == 0) rowinv[r] = 1.0f / sum;
        } else {
            for (int c = sub; c < cpad; c += 16) s[r][c] = 0.f;
        }
    }
    __syncthreads();

    // ---- PV via MFMA
    f32x4 o = {0.f, 0.f, 0.f, 0.f};
    {
        const int half = wave >> 1, par = wave & 1;
        const int kout = l16 + (half << 4);
        const int nchunk32 = cpad >> 5;
        const unsigned short* vrow = VT + (size_t)(h * HD + kout) * NPAD + ags + (lq << 3);
        for (int j = par; j < nchunk32; j += 2) {
            const int c0 = j << 5;
            const float4 p0 = *(const float4*)&s[l16][c0 + (lq << 3)];
            const float4 p1 = *(const float4*)&s[l16][c0 + (lq << 3) + 4];
            bf16x8 ap;
            ap[0] = f2b(p0.x); ap[1] = f2b(p0.y); ap[2] = f2b(p0.z); ap[3] = f2b(p0.w);
            ap[4] = f2b(p1.x); ap[5] = f2b(p1.y); ap[6] = f2b(p1.z); ap[7] = f2b(p1.w);
            bf16x8 bv = *(const bf16x8*)(vrow + c0);
            o = __builtin_amdgcn_mfma_f32_16x16x32_bf16(ap, bv, o, 0, 0, 0);
        }
    }
    __syncthreads();
    {
        float* red = &s[0][0];       // [4 waves][16 rows][16 kout], stride 17
        const int rbase = lq * 4;
        #pragma unroll
        for (int r = 0; r < 4; ++r)
            red[((wave << 4) + rbase + r) * 17 + l16] = o[r];
    }
    __syncthreads();
    {
        const int row = t >> 4, kl = t & 15;
        if (row < nrows) {
            float* red = &s[0][0];
            float v0 = red[(row) * 17 + kl]        + red[(16 + row) * 17 + kl];
            float v1 = red[(32 + row) * 17 + kl]   + red[(48 + row) * 17 + kl];
            float sc = rowinv[row];
            size_t ob = (size_t)(row0 + row) * DIM + h * HD;
            pre[ob + kl]      = v0 * sc;
            pre[ob + 16 + kl] = v1 * sc;
        }
    }

    // ---- arrival: fence own writes device-wide, bump tile counter (no spinning)
    __threadfence();
    __syncthreads();
    if (t == 0) {
        unsigned old = __hip_atomic_fetch_add(&pcnt[g * NTILE + tile_], 1u,
                                              __ATOMIC_ACQ_REL, __HIP_MEMORY_SCOPE_AGENT);
        isLast = (old == NH - 1);
    }
    __syncthreads();
    if (!isLast) return;
    __threadfence();                              // acquire all 8 heads' pre writes

    // ---- out projection for this 16-row tile (R6-validated epilogue, pre from global)
    {
        const int w = wave;
        const unsigned short* Wh = Wth + (size_t)3 * DIM * DIM;   // Wo^T
        const unsigned short* Wl = Wtl + (size_t)3 * DIM * DIM;
        const size_t arow = (size_t)(row0 + l16) * DIM + (lq << 3);

        f32x4 acc[4] = {{0,0,0,0},{0,0,0,0},{0,0,0,0},{0,0,0,0}};
        #pragma unroll
        for (int kc = 0; kc < 8; ++kc) {
            const int k = kc * 32;
            const float4 a0 = *(const float4*)&pre[arow + k];
            const float4 a1 = *(const float4*)&pre[arow + k + 4];
            bf16x8 ah, al;
            ah[0] = f2b(a0.x); al[0] = f2b(a0.x - b2f(ah[0]));
            ah[1] = f2b(a0.y); al[1] = f2b(a0.y - b2f(ah[1]));
            ah[2] = f2b(a0.z); al[2] = f2b(a0.z - b2f(ah[2]));
            ah[3] = f2b(a0.w); al[3] = f2b(a0.w - b2f(ah[3]));
            ah[4] = f2b(a1.x); al[4] = f2b(a1.x - b2f(ah[4]));
            ah[5] = f2b(a1.y); al[5] = f2b(a1.y - b2f(ah[5]));
            ah[6] = f2b(a1.z); al[6] = f2b(a1.z - b2f(ah[6]));
            ah[7] = f2b(a1.w); al[7] = f2b(a1.w - b2f(ah[7]));
            #pragma unroll
            for (int ct = 0; ct < 4; ++ct) {
                const size_t bo_ = (size_t)(w * 64 + ct * 16 + l16) * DIM + k + (lq << 3);
                bf16x8 bh = *(const bf16x8*)(Wh + bo_);
                bf16x8 bl = *(const bf16x8*)(Wl + bo_);
                acc[ct] = __builtin_amdgcn_mfma_f32_16x16x32_bf16(ah, bh, acc[ct], 0, 0, 0);
                acc[ct] = __builtin_amdgcn_mfma_f32_16x16x32_bf16(ah, bl, acc[ct], 0, 0, 0);
                acc[ct] = __builtin_amdgcn_mfma_f32_16x16x32_bf16(al, bh, acc[ct], 0, 0, 0);
            }
        }
        #pragma unroll
        for (int ct = 0; ct < 4; ++ct) {
            const int n = w * 64 + ct * 16 + l16;
            const float bvl = bo[n];
            #pragma unroll
            for (int r = 0; r < 4; ++r) {
                const int rr = lq * 4 + r;
                if (rr < nrows)
                    out[(size_t)(row0 + rr) * DIM + n] = acc[ct][r] + bvl;
            }
        }
    }
}

// ---------------- launch ----------------
extern "C" void kernel_launch(void* const* d_in, const int* in_sizes, int n_in,
                              void* d_out, int out_size, void* d_ws, size_t ws_size,
                              hipStream_t stream) {
    const float* x   = (const float*)d_in[0];
    const float* ea  = (const float*)d_in[1];
    const float* Wq  = (const float*)d_in[2];  const float* bq = (const float*)d_in[3];
    const float* Wk  = (const float*)d_in[4];  const float* bk = (const float*)d_in[5];
    const float* Wv  = (const float*)d_in[6];  const float* bv = (const float*)d_in[7];
    const float* Wo  = (const float*)d_in[8];  const float* bo = (const float*)d_in[9];
    const float* We  = (const float*)d_in[10]; const float* be = (const float*)d_in[11];
    const int*   eidx  = (const int*)d_in[12];
    const int*   batch = (const int*)d_in[13];
    const int* erow   = eidx;
    const int* ecolin = eidx + E_EDGES;

    const size_t ND = (size_t)N_NODES * DIM;     // 786432
    const size_t WD = (size_t)DIM * DIM;         // 65536

    unsigned short* Qb   = (unsigned short*)d_ws;
    unsigned short* Kb   = Qb + ND;
    unsigned short* VT   = Kb + ND;              // [256][NPAD]
    unsigned short* xh   = VT + (size_t)DIM * NPAD;
    unsigned short* xl   = xh + ND;
    unsigned short* Wth  = xl + ND;              // 4 * WD
    unsigned short* Wtl  = Wth + 4 * WD;
    unsigned int* tbuck  = (unsigned int*)(Wtl + 4 * WD);       // N_NODES * RCAP u32
    float* pre    = (float*)(tbuck + (size_t)N_NODES * RCAP);   // [N][256] fp32
    int* tcur     = (int*)(pre + ND);                           // N_NODES
    unsigned int* pcnt = (unsigned int*)(tcur + N_NODES);       // B*NTILE = 384
    int* gstart   = (int*)(pcnt + B_GRAPHS * NTILE);            // B+1

    prep_a<<<dim3(1038), dim3(256), 0, stream>>>(x, Wq, Wk, Wv, Wo,
                                                 xh, xl, Wth, Wtl, tcur, pcnt);
    stage2<<<dim3(1568), dim3(256), 0, stream>>>(xh, xl, Wth, Wtl, bq, bk, bv,
                                                 erow, ecolin, batch,
                                                 Qb, Kb, VT, gstart, tcur, tbuck);
    attn_go<<<dim3(B_GRAPHS, NTILE, NH), dim3(256), 0, stream>>>(
        Qb, Kb, VT, gstart, tcur, tbuck, ea, We, be,
        Wth, Wtl, bo, pre, pcnt, (float*)d_out);
}

// Round 8
// 149.511 us; speedup vs baseline: 2.2230x; 2.2230x over previous
//
#include <hip/hip_runtime.h>
#include <hip/hip_bf16.h>
#include <math.h>

#define N_NODES 3072
#define NPAD    3104    // V^T column stride: N + 32 zeroed pad cols (aligned PV loads)
#define DIM     256
#define NH      8
#define HD      32
#define E_EDGES 98304
#define B_GRAPHS 16
#define RCAP    96      // per-row bucket capacity (mean 32, 11-sigma margin; fixed seed)
#define MAXC    332     // fp32 score stride: 332*4=1328B rows (16B-aligned float4 P reads)
#define TR      16      // rows per attention tile
#define SCALE   0.17677669529663689f   // 1/sqrt(32)

// HW model note (R4/R7 measured): device-scope fences / ordered atomics serialize
// at ~60-120 ns each on MI355X — in-kernel grid sync with >1k blocks always costs
// >100 us. Dispatch boundaries (~4-12 us) are the cheap cross-XCD sync. 4 dispatches.

typedef __attribute__((ext_vector_type(8))) short bf16x8;
typedef __attribute__((ext_vector_type(4))) float f32x4;
typedef __attribute__((ext_vector_type(4))) unsigned short ushort4v;

__device__ inline unsigned short f2b(float f) {
    __hip_bfloat16 h = __float2bfloat16(f);
    return *reinterpret_cast<unsigned short*>(&h);
}
__device__ inline float b2f(unsigned short u) {
    __hip_bfloat16 h = *reinterpret_cast<__hip_bfloat16*>(&u);
    return __bfloat162float(h);
}
// hi/lo split of 8 fp32 (two float4) into bf16x8 pair — identical rounding to the
// old stored xh/xl split: ah=f2b(v), al=f2b(v-b2f(ah)).
__device__ inline void split8(const float4 a0, const float4 a1, bf16x8& ah, bf16x8& al) {
    ah[0] = f2b(a0.x); al[0] = f2b(a0.x - b2f(ah[0]));
    ah[1] = f2b(a0.y); al[1] = f2b(a0.y - b2f(ah[1]));
    ah[2] = f2b(a0.z); al[2] = f2b(a0.z - b2f(ah[2]));
    ah[3] = f2b(a0.w); al[3] = f2b(a0.w - b2f(ah[3]));
    ah[4] = f2b(a1.x); al[4] = f2b(a1.x - b2f(ah[4]));
    ah[5] = f2b(a1.y); al[5] = f2b(a1.y - b2f(ah[5]));
    ah[6] = f2b(a1.z); al[6] = f2b(a1.z - b2f(ah[6]));
    ah[7] = f2b(a1.w); al[7] = f2b(a1.w - b2f(ah[7]));
}

// ======================= phase bodies =========================================

__device__ inline void wtrans_body(int wb, int t,
                                   const float* __restrict__ Wq, const float* __restrict__ Wk,
                                   const float* __restrict__ Wv, const float* __restrict__ Wo,
                                   unsigned short* __restrict__ Wth,
                                   unsigned short* __restrict__ Wtl,
                                   float (*tile)[33]) {
    const int mat = wb >> 6, tidx = wb & 63;
    const int tk = (tidx >> 3) * 32, tn = (tidx & 7) * 32;
    const float* W = (mat == 0) ? Wq : (mat == 1) ? Wk : (mat == 2) ? Wv : Wo;
    const int kk = t >> 5, nn = t & 31;
    #pragma unroll
    for (int p = 0; p < 4; ++p)
        tile[nn][kk + p * 8] = W[(size_t)(tk + kk + p * 8) * DIM + tn + nn];
    __syncthreads();
    const int n = t >> 3, kq = (t & 7) * 4;
    ushort4v h, l;
    #pragma unroll
    for (int i = 0; i < 4; ++i) {
        float v = tile[n][kq + i];
        unsigned short hi = f2b(v);
        h[i] = hi;
        l[i] = f2b(v - b2f(hi));
    }
    size_t o = (size_t)mat * DIM * DIM + (size_t)(tn + n) * DIM + tk + kq;
    *(ushort4v*)(Wth + o) = h;
    *(ushort4v*)(Wtl + o) = l;
}

__device__ inline void vtpad_body(int i, const int* __restrict__ batch,
                                  unsigned short* __restrict__ VT,
                                  int* __restrict__ gstart) {
    VT[(size_t)(i >> 5) * NPAD + N_NODES + (i & 31)] = 0;   // i in [0, 8192)
    if (i < N_NODES) {
        int bb = batch[i];
        int bp = (i == 0) ? -1 : batch[i - 1];
        for (int g = bp + 1; g <= bb; ++g) gstart[g] = i;
        if (i == N_NODES - 1)
            for (int g = bb + 1; g <= B_GRAPHS; ++g) gstart[g] = N_NODES;
    }
}

// edge bucket insert only — bias is computed on the fly in attn (R7-proven bitwise).
__device__ inline void edge_body(int e,
                                 const int* __restrict__ erow, const int* __restrict__ ecolin,
                                 int* __restrict__ tcur, unsigned int* __restrict__ tbuck) {
    const int row = erow[e];
    const int col = ecolin[e];
    int pos = atomicAdd(&tcur[row], 1);
    if (pos < RCAP)
        tbuck[(size_t)row * RCAP + pos] = ((unsigned int)e << 12) | (unsigned int)col;
}

// wave tile 16x32; u in [0,1152): bx=u%96 (32-row block), by=u/96, mat=by>>2.
// x is read DIRECTLY in fp32 and hi/lo-split in registers (identical rounding to
// the old stored xh/xl) — the x-split phase and its 9 MB round-trip are gone.
__device__ inline void qkv_body(int u, int t,
                                const float* __restrict__ x,
                                const unsigned short* __restrict__ Wth, const unsigned short* __restrict__ Wtl,
                                const float* __restrict__ bq, const float* __restrict__ bk,
                                const float* __restrict__ bv,
                                unsigned short* __restrict__ Qb, unsigned short* __restrict__ Kb,
                                unsigned short* __restrict__ VT) {
    const int w = t >> 6, lane = t & 63;
    const int l16 = lane & 15, lq = lane >> 4;
    const int bx = u % 96, by = u / 96;
    const int mat = by >> 2;
    const int rb = bx * 32 + (w & 1) * 16;
    const int nb = (by & 3) * 64 + (w >> 1) * 32;
    const unsigned short* Wh = Wth + (size_t)mat * DIM * DIM;
    const unsigned short* Wl = Wtl + (size_t)mat * DIM * DIM;

    f32x4 acc[2] = {{0,0,0,0},{0,0,0,0}};

    if (mat < 2) {                       // ---- Q/K: A = x rows (fp32 split), B = W^T rows
        const size_t arow = (size_t)(rb + l16) * DIM + (lq << 3);
        #pragma unroll
        for (int kc = 0; kc < 8; ++kc) {
            const int k = kc * 32;
            const float4 a0 = *(const float4*)(x + arow + k);
            const float4 a1 = *(const float4*)(x + arow + k + 4);
            bf16x8 ah, al;
            split8(a0, a1, ah, al);
            #pragma unroll
            for (int ct = 0; ct < 2; ++ct) {
                const size_t bo_ = (size_t)(nb + ct * 16 + l16) * DIM + k + (lq << 3);
                bf16x8 bh = *(const bf16x8*)(Wh + bo_);
                bf16x8 bl = *(const bf16x8*)(Wl + bo_);
                acc[ct] = __builtin_amdgcn_mfma_f32_16x16x32_bf16(ah, bh, acc[ct], 0, 0, 0);
                acc[ct] = __builtin_amdgcn_mfma_f32_16x16x32_bf16(ah, bl, acc[ct], 0, 0, 0);
                acc[ct] = __builtin_amdgcn_mfma_f32_16x16x32_bf16(al, bh, acc[ct], 0, 0, 0);
            }
        }
        const float* bias = (mat == 0) ? bq : bk;
        unsigned short* outp = (mat == 0) ? Qb : Kb;
        #pragma unroll
        for (int ct = 0; ct < 2; ++ct) {
            const int n = nb + ct * 16 + l16;
            const float bvl = bias[n];
            #pragma unroll
            for (int r = 0; r < 4; ++r)
                outp[(size_t)(rb + lq * 4 + r) * DIM + n] = f2b(acc[ct][r] + bvl);
        }
    } else {                             // ---- V^T: A = Wv^T rows, B = x rows (fp32 split)
        const size_t brow = (size_t)(rb + l16) * DIM + (lq << 3);
        #pragma unroll
        for (int kc = 0; kc < 8; ++kc) {
            const int k = kc * 32;
            const float4 b0 = *(const float4*)(x + brow + k);
            const float4 b1 = *(const float4*)(x + brow + k + 4);
            bf16x8 bxh, bxl;
            split8(b0, b1, bxh, bxl);
            #pragma unroll
            for (int ct = 0; ct < 2; ++ct) {
                const size_t ao_ = (size_t)(nb + ct * 16 + l16) * DIM + k + (lq << 3);
                bf16x8 awh = *(const bf16x8*)(Wh + ao_);
                bf16x8 awl = *(const bf16x8*)(Wl + ao_);
                acc[ct] = __builtin_amdgcn_mfma_f32_16x16x32_bf16(awh, bxh, acc[ct], 0, 0, 0);
                acc[ct] = __builtin_amdgcn_mfma_f32_16x16x32_bf16(awh, bxl, acc[ct], 0, 0, 0);
                acc[ct] = __builtin_amdgcn_mfma_f32_16x16x32_bf16(awl, bxh, acc[ct], 0, 0, 0);
            }
        }
        #pragma unroll
        for (int ct = 0; ct < 2; ++ct) {
            #pragma unroll
            for (int r = 0; r < 4; ++r) {
                const int ncol = nb + ct * 16 + lq * 4 + r;   // output channel (h*HD+kout)
                VT[(size_t)ncol * NPAD + rb + l16] = f2b(acc[ct][r] + bv[ncol]);
            }
        }
    }
}

// ======================= node 1: W-trans | tcur zero ==========================
// grid 268: [0,256) W-transpose, [256,268) tcur zero. (x-split phase eliminated.)
__global__ __launch_bounds__(256) void prep_w(
    const float* __restrict__ Wq, const float* __restrict__ Wk,
    const float* __restrict__ Wv, const float* __restrict__ Wo,
    unsigned short* __restrict__ Wth, unsigned short* __restrict__ Wtl,
    int* __restrict__ tcur)
{
    __shared__ float tile[32][33];
    const int b = blockIdx.x, t = threadIdx.x;
    if (b < 256)  wtrans_body(b, t, Wq, Wk, Wv, Wo, Wth, Wtl, tile);
    else          tcur[(b - 256) * 256 + t] = 0;
}

// ======================= node 2: edges | qkv mfma | VT-pad/gstart =============
__global__ __launch_bounds__(256) void stage2(
    const float* __restrict__ x,
    const unsigned short* __restrict__ Wth, const unsigned short* __restrict__ Wtl,
    const float* __restrict__ bq, const float* __restrict__ bk,
    const float* __restrict__ bv,
    const int* __restrict__ erow, const int* __restrict__ ecolin,
    const int* __restrict__ batch,
    unsigned short* __restrict__ Qb, unsigned short* __restrict__ Kb,
    unsigned short* __restrict__ VT,
    int* __restrict__ gstart, int* __restrict__ tcur, unsigned int* __restrict__ tbuck)
{
    const int b = blockIdx.x, t = threadIdx.x;
    if (b < 384)        edge_body(b * 256 + t, erow, ecolin, tcur, tbuck);
    else if (b < 1536)  qkv_body(b - 384, t, x, Wth, Wtl, bq, bk, bv, Qb, Kb, VT);
    else                vtpad_body((b - 1536) * 256 + t, batch, VT, gstart);
}

// ======================= node 3: attention (on-the-fly bias) ==================
// grid (16,24,8), block 256. R3-proven structure; bias computed from ea/We/be
// inline (R7-proven bitwise). Output: split-bf16 preh/prel as in R3.
__global__ __launch_bounds__(256) void attn(
    const unsigned short* __restrict__ Qb, const unsigned short* __restrict__ Kb,
    const unsigned short* __restrict__ VT,
    const int* __restrict__ gstart,
    const int* __restrict__ tcur, const unsigned int* __restrict__ tbuck,
    const float* __restrict__ ea, const float* __restrict__ We,
    const float* __restrict__ be,
    unsigned short* __restrict__ preh, unsigned short* __restrict__ prel)
{
    __shared__ __align__(16) float s[TR][MAXC];   // scores fp32 -> P fp32 -> reduce buf
    __shared__ float rowinv[TR];

    const int g = blockIdx.x, tile_ = blockIdx.y, h = blockIdx.z;
    const int gs = gstart[g], ge = gstart[g + 1];
    const int row0 = gs + tile_ * TR;
    if (row0 >= ge) return;
    const int nrows = min(TR, ge - row0);
    const int ncols = ge - gs;
    const int ags   = gs & ~15;
    const int coff  = gs - ags;
    const int tcols = coff + ncols;
    const int cpad  = (tcols + 31) & ~31;
    const int t = threadIdx.x;
    const int wave = t >> 6, lane = t & 63;
    const int l16 = lane & 15, lq = lane >> 4;

    const float we0 = We[0 * NH + h], we1 = We[1 * NH + h];
    const float we2 = We[2 * NH + h], we3 = We[3 * NH + h];
    const float beh = be[h];

    // ---- QK^T via MFMA
    {
        int arow = min(row0 + l16, N_NODES - 1);
        const bf16x8 aq = *(const bf16x8*)(Qb + (size_t)arow * DIM + h * HD + (lq << 3));
        const int nchunk16 = (tcols + 15) >> 4;
        for (int j = wave; j < nchunk16; j += 4) {
            const int c0 = j << 4;
            int krow = min(ags + c0 + l16, N_NODES - 1);
            bf16x8 bk = *(const bf16x8*)(Kb + (size_t)krow * DIM + h * HD + (lq << 3));
            f32x4 d = {0.f, 0.f, 0.f, 0.f};
            d = __builtin_amdgcn_mfma_f32_16x16x32_bf16(aq, bk, d, 0, 0, 0);
            const int col = c0 + l16, rbase = lq * 4;
            #pragma unroll
            for (int r = 0; r < 4; ++r) s[rbase + r][col] = d[r] * SCALE;
        }
    }
    __syncthreads();

    // ---- edge-bias scatter, bias computed on the fly (same fmaf chain, bitwise)
    {
        const int r = t >> 4, sub = t & 15;
        if (r < nrows) {
            const int cnt = min(tcur[row0 + r], RCAP);
            const unsigned int* bk = tbuck + (size_t)(row0 + r) * RCAP;
            for (int idx = sub; idx < cnt; idx += 16) {
                unsigned int p = bk[idx];
                int c = (int)(p & 0xFFFu) - gs;
                if (c >= 0 && c < ncols) {
                    float4 a = ((const float4*)ea)[p >> 12];
                    float bb = fmaf(a.x, we0, fmaf(a.y, we1,
                               fmaf(a.z, we2, fmaf(a.w, we3, beh))));
                    atomicAdd(&s[r][coff + c], bb);
                }
            }
        }
    }
    __syncthreads();

    // ---- softmax, exp written back in place (fp32 P)
    {
        const int r = t >> 4, sub = t & 15;
        if (r < nrows) {
            float m = -INFINITY;
            for (int c = coff + sub; c < tcols; c += 16) m = fmaxf(m, s[r][c]);
            m = fmaxf(m, __shfl_xor(m, 1, 16));
            m = fmaxf(m, __shfl_xor(m, 2, 16));
            m = fmaxf(m, __shfl_xor(m, 4, 16));
            m = fmaxf(m, __shfl_xor(m, 8, 16));
            float sum = 0.f;
            for (int c = sub; c < cpad; c += 16) {
                float e = 0.f;
                if (c >= coff && c < tcols) e = __expf(s[r][c] - m);
                sum += e;
                s[r][c] = e;
            }
            sum += __shfl_xor(sum, 1, 16);
            sum += __shfl_xor(sum, 2, 16);
            sum += __shfl_xor(sum, 4, 16);
            sum += __shfl_xor(sum, 8, 16);
            if (sub == 0) rowinv[r] = 1.0f / sum;
        } else {
            for (int c = sub; c < cpad; c += 16) s[r][c] = 0.f;
        }
    }
    __syncthreads();

    // ---- PV via MFMA: A-frag = fp32 P from LDS, cvt in regs; B = V^T row
    f32x4 o = {0.f, 0.f, 0.f, 0.f};
    {
        const int half = wave >> 1, par = wave & 1;
        const int kout = l16 + (half << 4);
        const int nchunk32 = cpad >> 5;
        const unsigned short* vrow = VT + (size_t)(h * HD + kout) * NPAD + ags + (lq << 3);
        for (int j = par; j < nchunk32; j += 2) {
            const int c0 = j << 5;
            const float4 p0 = *(const float4*)&s[l16][c0 + (lq << 3)];
            const float4 p1 = *(const float4*)&s[l16][c0 + (lq << 3) + 4];
            bf16x8 ap;
            ap[0] = f2b(p0.x); ap[1] = f2b(p0.y); ap[2] = f2b(p0.z); ap[3] = f2b(p0.w);
            ap[4] = f2b(p1.x); ap[5] = f2b(p1.y); ap[6] = f2b(p1.z); ap[7] = f2b(p1.w);
            bf16x8 bv = *(const bf16x8*)(vrow + c0);
            o = __builtin_amdgcn_mfma_f32_16x16x32_bf16(ap, bv, o, 0, 0, 0);
        }
    }
    __syncthreads();
    {
        float* red = &s[0][0];       // [4 waves][16 rows][16 kout], stride 17
        const int rbase = lq * 4;
        #pragma unroll
        for (int r = 0; r < 4; ++r)
            red[((wave << 4) + rbase + r) * 17 + l16] = o[r];
    }
    __syncthreads();
    {
        const int row = t >> 4, kl = t & 15;
        if (row < nrows) {
            float* red = &s[0][0];
            float v0 = red[(row) * 17 + kl]        + red[(16 + row) * 17 + kl];
            float v1 = red[(32 + row) * 17 + kl]   + red[(48 + row) * 17 + kl];
            float sc = rowinv[row];
            size_t ob = (size_t)(row0 + row) * DIM + h * HD;
            float f0 = v0 * sc, f1 = v1 * sc;
            unsigned short h0 = f2b(f0), h1 = f2b(f1);
            preh[ob + kl]      = h0;
            preh[ob + 16 + kl] = h1;
            prel[ob + kl]      = f2b(f0 - b2f(h0));
            prel[ob + 16 + kl] = f2b(f1 - b2f(h1));
        }
    }
}

// ======================= node 4: output projection ============================
__global__ __launch_bounds__(256) void out_mfma(
    const unsigned short* __restrict__ preh, const unsigned short* __restrict__ prel,
    const unsigned short* __restrict__ Wth, const unsigned short* __restrict__ Wtl,
    const float* __restrict__ bo, float* __restrict__ out)
{
    const int t = threadIdx.x, w = t >> 6, lane = t & 63;
    const int l16 = lane & 15, lq = lane >> 4;
    const int rb = blockIdx.x * 16;
    const int nb = blockIdx.y * 128 + w * 32;
    const unsigned short* Wh = Wth + (size_t)3 * DIM * DIM;   // Wo^T
    const unsigned short* Wl = Wtl + (size_t)3 * DIM * DIM;

    f32x4 acc[2] = {{0,0,0,0},{0,0,0,0}};
    const size_t arow = (size_t)(rb + l16) * DIM + (lq << 3);

    #pragma unroll
    for (int kc = 0; kc < 8; ++kc) {
        const int k = kc * 32;
        bf16x8 ah = *(const bf16x8*)(preh + arow + k);
        bf16x8 al = *(const bf16x8*)(prel + arow + k);
        #pragma unroll
        for (int ct = 0; ct < 2; ++ct) {
            const size_t bo_ = (size_t)(nb + ct * 16 + l16) * DIM + k + (lq << 3);
            bf16x8 bh = *(const bf16x8*)(Wh + bo_);
            bf16x8 bl = *(const bf16x8*)(Wl + bo_);
            acc[ct] = __builtin_amdgcn_mfma_f32_16x16x32_bf16(ah, bh, acc[ct], 0, 0, 0);
            acc[ct] = __builtin_amdgcn_mfma_f32_16x16x32_bf16(ah, bl, acc[ct], 0, 0, 0);
            acc[ct] = __builtin_amdgcn_mfma_f32_16x16x32_bf16(al, bh, acc[ct], 0, 0, 0);
        }
    }

    #pragma unroll
    for (int ct = 0; ct < 2; ++ct) {
        const int n = nb + ct * 16 + l16;
        const float bvl = bo[n];
        #pragma unroll
        for (int r = 0; r < 4; ++r)
            out[(size_t)(rb + lq * 4 + r) * DIM + n] = acc[ct][r] + bvl;
    }
}

// ---------------- launch ----------------
extern "C" void kernel_launch(void* const* d_in, const int* in_sizes, int n_in,
                              void* d_out, int out_size, void* d_ws, size_t ws_size,
                              hipStream_t stream) {
    const float* x   = (const float*)d_in[0];
    const float* ea  = (const float*)d_in[1];
    const float* Wq  = (const float*)d_in[2];  const float* bq = (const float*)d_in[3];
    const float* Wk  = (const float*)d_in[4];  const float* bk = (const float*)d_in[5];
    const float* Wv  = (const float*)d_in[6];  const float* bv = (const float*)d_in[7];
    const float* Wo  = (const float*)d_in[8];  const float* bo = (const float*)d_in[9];
    const float* We  = (const float*)d_in[10]; const float* be = (const float*)d_in[11];
    const int*   eidx  = (const int*)d_in[12];
    const int*   batch = (const int*)d_in[13];
    const int* erow   = eidx;
    const int* ecolin = eidx + E_EDGES;

    const size_t ND = (size_t)N_NODES * DIM;     // 786432
    const size_t WD = (size_t)DIM * DIM;         // 65536

    unsigned short* Qb   = (unsigned short*)d_ws;
    unsigned short* Kb   = Qb + ND;
    unsigned short* VT   = Kb + ND;              // [256][NPAD]
    unsigned short* preh = VT + (size_t)DIM * NPAD;
    unsigned short* prel = preh + ND;
    unsigned short* Wth  = prel + ND;            // 4 * WD
    unsigned short* Wtl  = Wth + 4 * WD;
    unsigned int* tbuck  = (unsigned int*)(Wtl + 4 * WD);       // N_NODES * RCAP u32
    int* tcur     = (int*)(tbuck + (size_t)N_NODES * RCAP);     // N_NODES
    int* gstart   = tcur + N_NODES;                             // B+1

    prep_w<<<dim3(268), dim3(256), 0, stream>>>(Wq, Wk, Wv, Wo, Wth, Wtl, tcur);
    stage2<<<dim3(1568), dim3(256), 0, stream>>>(x, Wth, Wtl, bq, bk, bv,
                                                 erow, ecolin, batch,
                                                 Qb, Kb, VT, gstart, tcur, tbuck);
    attn<<<dim3(B_GRAPHS, 24, NH), dim3(256), 0, stream>>>(Qb, Kb, VT, gstart,
                                                           tcur, tbuck, ea, We, be,
                                                           preh, prel);
    out_mfma<<<dim3(192, 2), dim3(256), 0, stream>>>(preh, prel, Wth, Wtl, bo, (float*)d_out);
}